// Round 6
// baseline (19532.324 us; speedup 1.0000x reference)
//
#include <hip/hip_runtime.h>
#include <cstddef>

#define B_ 128
#define S_ 512
#define I_ 1024
#define H_ 1024
#define G4_ 4096

typedef __attribute__((ext_vector_type(8))) short bf16x8;   // 8 bf16 = 4 VGPR
typedef __attribute__((ext_vector_type(4))) float f32x4;
typedef unsigned short u16;
typedef unsigned int   u32;

// round-to-nearest bf16 (bit trick; half-up, bias negligible)
__device__ inline u16 bf16_rn(float x) {
  return (u16)((__float_as_uint(x) + 0x8000u) >> 16);
}
// rounded hi + exact residual
__device__ inline u16 bf16_hi_rem(float x, float& rem) {
  const u32 hb = (__float_as_uint(x) + 0x8000u) & 0xFFFF0000u;
  rem = x - __uint_as_float(hb);
  return (u16)(hb >> 16);
}

// ---------------------------------------------------------------- zero init
__global__ __launch_bounds__(256) void k_zero(float* __restrict__ p, int n) {
  int i = blockIdx.x * 256 + threadIdx.x;
  if (i < n) p[i] = 0.0f;
}

// ---------------------------------------------------------------- W split+transpose
// z 0..3: Wxt[n' = j*4+z][k] = Wg_xpart[k][j]      (gate-interleaved)
// z == 4: Wot[n  = j     ][k] = Wout[k][j]
// z 5..8: Wht[n' = j*4+(z-5)][k] = Wg_hpart[k][j]  (gate-interleaved)
// grid (16 k-tiles, 16 j-tiles, 9), 64x64 LDS tile transpose, hi/lo bf16 out.
__global__ __launch_bounds__(256) void k_tr(
    const float* __restrict__ Wf, const float* __restrict__ Wi,
    const float* __restrict__ Wc, const float* __restrict__ Wo,
    const float* __restrict__ Wout,
    u16* __restrict__ Wxt_hi, u16* __restrict__ Wxt_lo,
    u16* __restrict__ Wot_hi, u16* __restrict__ Wot_lo,
    u16* __restrict__ Wht_hi, u16* __restrict__ Wht_lo)
{
  __shared__ float T_[64][65];
  const int kt = blockIdx.x, jt = blockIdx.y, z = blockIdx.z;
  const int g = (z < 4) ? z : (z - 5);
  const float* src = (z == 4) ? Wout
                   : (g == 0) ? Wf : (g == 1) ? Wi : (g == 2) ? Wc : Wo;
  u16* dh = (z < 4) ? Wxt_hi : (z == 4) ? Wot_hi : Wht_hi;
  u16* dl = (z < 4) ? Wxt_lo : (z == 4) ? Wot_lo : Wht_lo;
  const int rowbase = ((z >= 5) ? I_ : 0) + kt * 64;
  const int tid = threadIdx.x;

#pragma unroll
  for (int it = 0; it < 4; ++it) {
    const int idx = it * 1024 + tid * 4;      // float4 granule
    const int a = idx >> 6, c = idx & 63;     // a = k-row, c = j-col
    const float4 v = *(const float4*)(src + (size_t)(rowbase + a) * 1024 + jt * 64 + c);
    T_[a][c] = v.x; T_[a][c + 1] = v.y; T_[a][c + 2] = v.z; T_[a][c + 3] = v.w;
  }
  __syncthreads();
#pragma unroll
  for (int it = 0; it < 16; ++it) {
    const int idx = it * 256 + tid;
    const int j = idx >> 6, k = idx & 63;     // lanes -> consecutive k (coalesced)
    const float xv = T_[k][j];
    float rem;
    const u16 hi = bf16_hi_rem(xv, rem);
    const u16 lo = bf16_rn(rem);
    size_t o;
    if (z == 4) o = (size_t)(jt * 64 + j) * 1024 + kt * 64 + k;
    else        o = ((size_t)(jt * 64 + j) * 4 + g) * 1024 + kt * 64 + k;
    dh[o] = hi; dl[o] = lo;
  }
}

// ---------------------------------------------------------------- gate-bias concat (n' = j*4+g)
__global__ __launch_bounds__(256) void k_bias(
    const float* __restrict__ b0, const float* __restrict__ b1,
    const float* __restrict__ b2, const float* __restrict__ b3,
    float* __restrict__ b4)
{
  const int i = blockIdx.x * 256 + threadIdx.x;     // [0,4096)
  const int g = i & 3, j = i >> 2;
  const float* s = (g == 0) ? b0 : (g == 1) ? b1 : (g == 2) ? b2 : b3;
  b4[i] = s[j];
}

// ---------------------------------------------------------------- x split (per chunk)
// xs_hi/lo[(tl*128 + b)][k] = split(x[b][t0+tl][k]). grid (64, T).
__global__ __launch_bounds__(256) void k_xsplit(
    const float* __restrict__ x, u16* __restrict__ xh, u16* __restrict__ xl, int t0)
{
  const int id = blockIdx.x * 256 + threadIdx.x;    // [0, 16384)
  const int tl = blockIdx.y;
  const int b  = id >> 7;
  const int k8 = (id & 127) << 3;
  const float* s = x + ((size_t)b * 512 + (size_t)(t0 + tl)) * 1024 + k8;
  const float4 v0 = *(const float4*)(s);
  const float4 v1 = *(const float4*)(s + 4);
  const float vs[8] = {v0.x, v0.y, v0.z, v0.w, v1.x, v1.y, v1.z, v1.w};
  u32 hw[4], lw[4];
#pragma unroll
  for (int p = 0; p < 4; ++p) {
    float r0, r1;
    const u16 h0 = bf16_hi_rem(vs[2 * p], r0);
    const u16 h1 = bf16_hi_rem(vs[2 * p + 1], r1);
    hw[p] = (u32)h0 | ((u32)h1 << 16);
    lw[p] = (u32)bf16_rn(r0) | ((u32)bf16_rn(r1) << 16);
  }
  const size_t o = ((size_t)tl * 128 + b) * 1024 + k8;
  *(uint4*)(xh + o) = make_uint4(hw[0], hw[1], hw[2], hw[3]);
  *(uint4*)(xl + o) = make_uint4(lw[0], lw[1], lw[2], lw[3]);
}

// ---------------------------------------------------------------- MFMA GEMM
// C[M=T*128][N] = A[M][1024] @ B[N][1024]^T + bias, A/B pre-split bf16 (n-major, k-contig).
// MODE 0 (pre-gates): N=4096 (n'-order), bf16x3; C=preC[(tl*128+b)][4096].
// MODE 1 (out-proj):  N=1024, single product, C=out[b][t0+tl][1024].
// 128x128 tile, BK=32, 256 thr = 4 waves (2x2), per wave 4x4 frags of 16x16x32.
template<int MODE>
__global__ __launch_bounds__(256) void k_gemm_mfma(
    const u16* __restrict__ Ahg, const u16* __restrict__ Alg,
    const u16* __restrict__ Bhg, const u16* __restrict__ Blg,
    const float* __restrict__ bias,
    float* __restrict__ C, int t0)
{
  __shared__ u16 Ah[4096], Al[4096], Bh[4096], Bl[4096];
  const int tid = threadIdx.x;
  const int n0  = blockIdx.x * 128;
  const int by  = blockIdx.y;                 // = tl (one timestep per M-tile)

  const int w = tid >> 6, lane = tid & 63;
  const int wm = w >> 1, wn = w & 1;
  const int lr = lane & 15, lh = lane >> 4;   // frag row/col, k-half

  f32x4 acc[4][4];
#pragma unroll
  for (int mi = 0; mi < 4; ++mi)
#pragma unroll
    for (int ni = 0; ni < 4; ++ni) acc[mi][ni] = (f32x4){0.f, 0.f, 0.f, 0.f};

  const int srow  = tid >> 1;
  const int sb    = (tid & 1) * 2;
  const int swz   = (srow >> 1) & 3;
  const int l0 = srow * 32 + ((sb ^ swz) << 3);
  const int l1 = srow * 32 + (((sb + 1) ^ swz) << 3);
  const size_t ga = (size_t)(by * 128 + srow) * 1024 + (sb << 3);
  const size_t gb = (size_t)(n0 + srow) * 1024 + (sb << 3);

  int aoff[4], boff[4];
#pragma unroll
  for (int mi = 0; mi < 4; ++mi) {
    const int R = wm * 64 + mi * 16 + lr;
    aoff[mi] = R * 32 + ((lh ^ ((R >> 1) & 3)) << 3);
  }
#pragma unroll
  for (int ni = 0; ni < 4; ++ni) {
    const int Rn = wn * 64 + ni * 16 + lr;
    boff[ni] = Rn * 32 + ((lh ^ ((Rn >> 1) & 3)) << 3);
  }

  for (int k0 = 0; k0 < 1024; k0 += 32) {
    const uint4 vah0 = *(const uint4*)(Ahg + ga + k0);
    const uint4 vah1 = *(const uint4*)(Ahg + ga + k0 + 8);
    const uint4 vbh0 = *(const uint4*)(Bhg + gb + k0);
    const uint4 vbh1 = *(const uint4*)(Bhg + gb + k0 + 8);
    uint4 val0, val1, vbl0, vbl1;
    if (MODE == 0) {
      val0 = *(const uint4*)(Alg + ga + k0);
      val1 = *(const uint4*)(Alg + ga + k0 + 8);
      vbl0 = *(const uint4*)(Blg + gb + k0);
      vbl1 = *(const uint4*)(Blg + gb + k0 + 8);
    }
    __syncthreads();
    *(uint4*)(Ah + l0) = vah0; *(uint4*)(Ah + l1) = vah1;
    *(uint4*)(Bh + l0) = vbh0; *(uint4*)(Bh + l1) = vbh1;
    if (MODE == 0) {
      *(uint4*)(Al + l0) = val0; *(uint4*)(Al + l1) = val1;
      *(uint4*)(Bl + l0) = vbl0; *(uint4*)(Bl + l1) = vbl1;
    }
    __syncthreads();

    bf16x8 ahf[4], alf[4];
#pragma unroll
    for (int mi = 0; mi < 4; ++mi) {
      ahf[mi] = *(const bf16x8*)(&Ah[aoff[mi]]);
      if (MODE == 0) alf[mi] = *(const bf16x8*)(&Al[aoff[mi]]);
    }
#pragma unroll
    for (int ni = 0; ni < 4; ++ni) {
      const bf16x8 bhf = *(const bf16x8*)(&Bh[boff[ni]]);
      bf16x8 blf;
      if (MODE == 0) blf = *(const bf16x8*)(&Bl[boff[ni]]);
#pragma unroll
      for (int mi = 0; mi < 4; ++mi) {
        acc[mi][ni] = __builtin_amdgcn_mfma_f32_16x16x32_bf16(ahf[mi], bhf, acc[mi][ni], 0, 0, 0);
        if (MODE == 0) {
          acc[mi][ni] = __builtin_amdgcn_mfma_f32_16x16x32_bf16(ahf[mi], blf, acc[mi][ni], 0, 0, 0);
          acc[mi][ni] = __builtin_amdgcn_mfma_f32_16x16x32_bf16(alf[mi], bhf, acc[mi][ni], 0, 0, 0);
        }
      }
    }
  }

#pragma unroll
  for (int ni = 0; ni < 4; ++ni) {
    const int n = n0 + wn * 64 + ni * 16 + lr;
    const float bv = bias[n];
#pragma unroll
    for (int mi = 0; mi < 4; ++mi) {
      const int rb = wm * 64 + mi * 16 + lh * 4;
#pragma unroll
      for (int q = 0; q < 4; ++q) {
        const int r = rb + q;
        const float v = acc[mi][ni][q] + bv;
        if (MODE == 0) C[((size_t)by * 128 + r) * 4096 + n] = v;
        else           C[((size_t)r * 512 + (size_t)(t0 + by)) * 1024 + n] = v;
      }
    }
  }
}

// ---------------------------------------------------------------- MFMA scan step
// 256 blocks (jt 0..63 x mq 0..3) x 512 thr (8 waves). No LDS, no barriers.
// Wave w: m-frag mi=w&1 (rows mq*32+mi*16..+15), n-frag nf=w>>1 (cols jt*64+nf*16..+15
// of Wht n'-order = 4 j x 4 gates). bf16x3: AhBh + AhBl + AlBh, fp32 acc.
// Epilogue: 12 shfl_xor gather the 4 gates per (b,j) cell; each lane owns 1 cell.
__global__ __launch_bounds__(512) void k_step3(
    const u16* __restrict__ Whh, const u16* __restrict__ Whl,   // Wht hi/lo [4096][1024]
    const float* __restrict__ preC,       // [Tc][128][4096] n'-order
    const u16* __restrict__ hIh, const u16* __restrict__ hIl,   // h in, [128][1024]
    u16* __restrict__ hOh, u16* __restrict__ hOl,               // h out
    float* __restrict__ hT,               // fp32 h [j*128+b] (final output)
    float* __restrict__ cb, float* __restrict__ nb, float* __restrict__ mb,
    u16* __restrict__ hAllH,              // [Tc*128][1024] bf16 (out-GEMM A)
    int t_local)
{
  const int tid = threadIdx.x;
  const int bid = blockIdx.x;
  const int jt = bid >> 2, mq = bid & 3;
  const int w = tid >> 6, lane = tid & 63;
  const int mi = w & 1, nf = w >> 1;
  const int lr = lane & 15, lh = lane >> 4;
  const int rowb = mq * 32 + mi * 16;

  // this lane's epilogue cell
  const int G = lr & 3;                       // gate role / q-partition
  const int j = jt * 16 + nf * 4 + (lr >> 2);
  const int b = rowb + lh * 4 + G;
  const int sIdx = j * 128 + b;

  // prefetch pre-gates (one float4: n' = j*4 + g) and state
  const float4 pre4 = *(const float4*)(preC + (size_t)t_local * (128 * 4096)
                                       + (size_t)b * 4096 + j * 4);
  const float m_old = mb[sIdx];
  const float c_old = cb[sIdx];
  const float n_old = nb[sIdx];

  // fragment base pointers (16B-aligned; all frag loads are L2-resident)
  const u16* aH = hIh + (size_t)(rowb + lr) * 1024 + lh * 8;
  const u16* aL = hIl + (size_t)(rowb + lr) * 1024 + lh * 8;
  const u16* bH = Whh + (size_t)(jt * 64 + nf * 16 + lr) * 1024 + lh * 8;
  const u16* bL = Whl + (size_t)(jt * 64 + nf * 16 + lr) * 1024 + lh * 8;

  f32x4 acc = {0.f, 0.f, 0.f, 0.f};
#pragma unroll 4
  for (int k0 = 0; k0 < 1024; k0 += 32) {
    const bf16x8 ah = *(const bf16x8*)(aH + k0);
    const bf16x8 al = *(const bf16x8*)(aL + k0);
    const bf16x8 bh = *(const bf16x8*)(bH + k0);
    const bf16x8 bl = *(const bf16x8*)(bL + k0);
    acc = __builtin_amdgcn_mfma_f32_16x16x32_bf16(ah, bh, acc, 0, 0, 0);
    acc = __builtin_amdgcn_mfma_f32_16x16x32_bf16(ah, bl, acc, 0, 0, 0);
    acc = __builtin_amdgcn_mfma_f32_16x16x32_bf16(al, bh, acc, 0, 0, 0);
  }

  // gather 4 gates per cell: gate t value = s_{G^t}[G] (all compile-time per case)
  const float a0 = acc[0], a1 = acc[1], a2 = acc[2], a3 = acc[3];
  const float s10 = __shfl_xor(a0, 1), s11 = __shfl_xor(a1, 1),
              s12 = __shfl_xor(a2, 1), s13 = __shfl_xor(a3, 1);
  const float s20 = __shfl_xor(a0, 2), s21 = __shfl_xor(a1, 2),
              s22 = __shfl_xor(a2, 2), s23 = __shfl_xor(a3, 2);
  const float s30 = __shfl_xor(a0, 3), s31 = __shfl_xor(a1, 3),
              s32 = __shfl_xor(a2, 3), s33 = __shfl_xor(a3, 3);
  float fv, iv, cv, ov;
  if      (G == 0) { fv = a0;  iv = s10; cv = s20; ov = s30; }
  else if (G == 1) { fv = s11; iv = a1;  cv = s31; ov = s21; }
  else if (G == 2) { fv = s22; iv = s32; cv = a2;  ov = s12; }
  else             { fv = s33; iv = s23; cv = s13; ov = a3;  }

  // fused elementwise state update
  const float f_log = fv + pre4.x;
  const float i_log = iv + pre4.y;
  const float c_log = cv + pre4.z;
  const float o_log = ov + pre4.w;

  const float m_new = fmaxf(f_log + m_old, i_log);
  const float i_t   = expf(i_log - m_new);
  const float f_t   = expf(f_log + m_old - m_new);
  const float c_hat = tanhf(c_log);
  const float o_t   = 1.0f / (1.0f + expf(-o_log));
  const float c_new = f_t * c_old + i_t * c_hat;
  const float n_new = f_t * n_old + i_t;
  const float h_new = o_t * (c_new / (n_new + 1e-8f));

  cb[sIdx] = c_new;
  nb[sIdx] = n_new;
  mb[sIdx] = m_new;
  hT[sIdx] = h_new;                               // fp32 (final-state output)

  float rem;
  const u16 hh = bf16_hi_rem(h_new, rem);
  const u16 hl = bf16_rn(rem);
  hOh[(size_t)b * 1024 + j] = hh;                 // recurrence h hi/lo
  hOl[(size_t)b * 1024 + j] = hl;
  hAllH[((size_t)t_local * 128 + b) * 1024 + j] = hh;
}

// ---------------------------------------------------------------- final state tail
__global__ __launch_bounds__(256) void k_tail(
    const float* __restrict__ hT, const float* __restrict__ cbp,
    const float* __restrict__ nbp, const float* __restrict__ mbp,
    float* __restrict__ dst)
{
  const int gid = blockIdx.x * 256 + threadIdx.x;   // [0, 4*131072)
  const int q = gid >> 17, rem = gid & 131071;
  const int b = rem >> 10, j = rem & 1023;
  const float* src = (q == 0) ? hT : (q == 1) ? cbp : (q == 2) ? nbp : mbp;
  dst[gid] = src[j * B_ + b];
}

// ---------------------------------------------------------------- launch
extern "C" void kernel_launch(void* const* d_in, const int* in_sizes, int n_in,
                              void* d_out, int out_size, void* d_ws, size_t ws_size,
                              hipStream_t stream) {
  const float* x    = (const float*)d_in[0];
  const float* Wf   = (const float*)d_in[1];
  const float* bfv  = (const float*)d_in[2];
  const float* Wi   = (const float*)d_in[3];
  const float* biv  = (const float*)d_in[4];
  const float* Wc   = (const float*)d_in[5];
  const float* bcv  = (const float*)d_in[6];
  const float* Wo   = (const float*)d_in[7];
  const float* bov  = (const float*)d_in[8];
  const float* Wout = (const float*)d_in[9];
  const float* bout = (const float*)d_in[10];
  float* out = (float*)d_out;

  float* base = (float*)d_ws;
  float* hT = base;                       // 131072 f
  float* cb = base + 131072;
  float* nb = base + 2 * 131072;
  float* mb = base + 3 * 131072;
  u16* hH0h = (u16*)(base + 4 * 131072);  // 4 x 131072 u16 = 2*131072 f
  u16* hH0l = hH0h + 131072;
  u16* hH1h = hH0l + 131072;
  u16* hH1l = hH1h + 131072;
  u16* Wxt_hi = (u16*)(base + 6 * 131072);
  u16* Wxt_lo = Wxt_hi + 4194304;
  u16* Wht_hi = Wxt_lo + 4194304;
  u16* Wht_lo = Wht_hi + 4194304;
  u16* Wot_hi = Wht_lo + 4194304;
  u16* Wot_lo = Wot_hi + 1048576;
  float* bias4  = (float*)(Wot_lo + 1048576);
  float* chunk0 = bias4 + 4096;

  const size_t fixedF = (size_t)6 * 131072      // states + h bufs
                      + 4 * 2097152             // Wxt + Wht hi/lo (f-equiv)
                      + 2 * 524288 / 2 * 2      // Wot hi/lo (1048576 u16 = 524288 f... keep explicit below
                      ;
  // explicit: 6*131072 + (4*4194304 + 2*1048576) u16 /2 + 4096
  const size_t fixedF2 = (size_t)6 * 131072
                       + ((size_t)4 * 4194304 + 2 * 1048576) / 2
                       + 4096;
  // per timestep: preC 2MB + xs hi/lo 0.5MB + hAllH 0.25MB = 720896 floats
  const size_t perTF = (size_t)128 * 4096 + 3 * 65536;
  const size_t availF = (ws_size / 4 > fixedF2) ? (ws_size / 4 - fixedF2) : 0;
  int Tc = (int)(availF / perTF);
  if (Tc > S_) Tc = S_;
  if (Tc < 1)  Tc = 1;
  (void)fixedF;

  float* preC   = chunk0;                               // [Tc][128][4096] n'-order
  u16*   xs_hi  = (u16*)(preC + (size_t)Tc * 524288);   // [Tc*128][1024]
  u16*   xs_lo  = xs_hi + (size_t)Tc * 131072;
  u16*   hAll_h = xs_lo + (size_t)Tc * 131072;          // [Tc*128][1024]

  u16* hHi[2] = {hH0h, hH1h};
  u16* hLo[2] = {hH0l, hH1l};

  // one-time prep: zero c/n/m + h(0) hi/lo; build W operand images + bias
  k_zero<<<2048, 256, 0, stream>>>(cb, 4 * 131072);     // cb,nb,mb + hH0h,hH0l
  k_tr<<<dim3(16, 16, 9), 256, 0, stream>>>(Wf, Wi, Wc, Wo, Wout,
                                            Wxt_hi, Wxt_lo, Wot_hi, Wot_lo,
                                            Wht_hi, Wht_lo);
  k_bias<<<16, 256, 0, stream>>>(bfv, biv, bcv, bov, bias4);

  for (int t0 = 0; t0 < S_; t0 += Tc) {
    const int T = (S_ - t0 < Tc) ? (S_ - t0) : Tc;

    k_xsplit<<<dim3(64, T), 256, 0, stream>>>(x, xs_hi, xs_lo, t0);
    k_gemm_mfma<0><<<dim3(32, T), 256, 0, stream>>>(xs_hi, xs_lo, Wxt_hi, Wxt_lo,
                                                    bias4, preC, t0);
    for (int tl = 0; tl < T; ++tl) {
      const int tg = t0 + tl;
      const int ri = tg & 1, wi = ri ^ 1;
      k_step3<<<256, 512, 0, stream>>>(Wht_hi, Wht_lo, preC,
                                       hHi[ri], hLo[ri], hHi[wi], hLo[wi],
                                       hT, cb, nb, mb, hAll_h, tl);
    }
    k_gemm_mfma<1><<<dim3(8, T), 256, 0, stream>>>(hAll_h, hAll_h, Wot_hi, Wot_hi,
                                                   bout, out, t0);
  }

  k_tail<<<2048, 256, 0, stream>>>(hT, cb, nb, mb, out + (size_t)B_ * S_ * H_);
}

// Round 8
// 18914.461 us; speedup vs baseline: 1.0327x; 1.0327x over previous
//
#include <hip/hip_runtime.h>
#include <cstddef>

#define B_ 128
#define S_ 512
#define I_ 1024
#define H_ 1024
#define G4_ 4096

typedef __attribute__((ext_vector_type(8))) short bf16x8;   // 8 bf16 = 4 VGPR
typedef __attribute__((ext_vector_type(4))) float f32x4;
typedef unsigned short u16;
typedef unsigned int   u32;

// round-to-nearest bf16 (bit trick; half-up, bias negligible)
__device__ inline u16 bf16_rn(float x) {
  return (u16)((__float_as_uint(x) + 0x8000u) >> 16);
}
// rounded hi + exact residual
__device__ inline u16 bf16_hi_rem(float x, float& rem) {
  const u32 hb = (__float_as_uint(x) + 0x8000u) & 0xFFFF0000u;
  rem = x - __uint_as_float(hb);
  return (u16)(hb >> 16);
}

// ---------------------------------------------------------------- zero init
__global__ __launch_bounds__(256) void k_zero(float* __restrict__ p, int n) {
  int i = blockIdx.x * 256 + threadIdx.x;
  if (i < n) p[i] = 0.0f;
}

// ---------------------------------------------------------------- W split+transpose
// z 0..3: Wxt[n' = j*4+z][k] = Wg_xpart[k][j]      (gate-interleaved)
// z == 4: Wot[n  = j     ][k] = Wout[k][j]
// z 5..8: Wht[n' = j*4+(z-5)][k] = Wg_hpart[k][j]  (gate-interleaved)
// grid (16 k-tiles, 16 j-tiles, 9), 64x64 LDS tile transpose, hi/lo bf16 out.
__global__ __launch_bounds__(256) void k_tr(
    const float* __restrict__ Wf, const float* __restrict__ Wi,
    const float* __restrict__ Wc, const float* __restrict__ Wo,
    const float* __restrict__ Wout,
    u16* __restrict__ Wxt_hi, u16* __restrict__ Wxt_lo,
    u16* __restrict__ Wot_hi, u16* __restrict__ Wot_lo,
    u16* __restrict__ Wht_hi, u16* __restrict__ Wht_lo)
{
  __shared__ float T_[64][65];
  const int kt = blockIdx.x, jt = blockIdx.y, z = blockIdx.z;
  const int g = (z < 4) ? z : (z - 5);
  const float* src = (z == 4) ? Wout
                   : (g == 0) ? Wf : (g == 1) ? Wi : (g == 2) ? Wc : Wo;
  u16* dh = (z < 4) ? Wxt_hi : (z == 4) ? Wot_hi : Wht_hi;
  u16* dl = (z < 4) ? Wxt_lo : (z == 4) ? Wot_lo : Wht_lo;
  const int rowbase = ((z >= 5) ? I_ : 0) + kt * 64;
  const int tid = threadIdx.x;

#pragma unroll
  for (int it = 0; it < 4; ++it) {
    const int idx = it * 1024 + tid * 4;      // float4 granule
    const int a = idx >> 6, c = idx & 63;     // a = k-row, c = j-col
    const float4 v = *(const float4*)(src + (size_t)(rowbase + a) * 1024 + jt * 64 + c);
    T_[a][c] = v.x; T_[a][c + 1] = v.y; T_[a][c + 2] = v.z; T_[a][c + 3] = v.w;
  }
  __syncthreads();
#pragma unroll
  for (int it = 0; it < 16; ++it) {
    const int idx = it * 256 + tid;
    const int j = idx >> 6, k = idx & 63;     // lanes -> consecutive k (coalesced)
    const float xv = T_[k][j];
    float rem;
    const u16 hi = bf16_hi_rem(xv, rem);
    const u16 lo = bf16_rn(rem);
    size_t o;
    if (z == 4) o = (size_t)(jt * 64 + j) * 1024 + kt * 64 + k;
    else        o = ((size_t)(jt * 64 + j) * 4 + g) * 1024 + kt * 64 + k;
    dh[o] = hi; dl[o] = lo;
  }
}

// ---------------------------------------------------------------- gate-bias concat (n' = j*4+g)
__global__ __launch_bounds__(256) void k_bias(
    const float* __restrict__ b0, const float* __restrict__ b1,
    const float* __restrict__ b2, const float* __restrict__ b3,
    float* __restrict__ b4)
{
  const int i = blockIdx.x * 256 + threadIdx.x;     // [0,4096)
  const int g = i & 3, j = i >> 2;
  const float* s = (g == 0) ? b0 : (g == 1) ? b1 : (g == 2) ? b2 : b3;
  b4[i] = s[j];
}

// ---------------------------------------------------------------- x split (per chunk)
// xs_hi/lo[(tl*128 + b)][k] = split(x[b][t0+tl][k]). grid (64, T).
__global__ __launch_bounds__(256) void k_xsplit(
    const float* __restrict__ x, u16* __restrict__ xh, u16* __restrict__ xl, int t0)
{
  const int id = blockIdx.x * 256 + threadIdx.x;    // [0, 16384)
  const int tl = blockIdx.y;
  const int b  = id >> 7;
  const int k8 = (id & 127) << 3;
  const float* s = x + ((size_t)b * 512 + (size_t)(t0 + tl)) * 1024 + k8;
  const float4 v0 = *(const float4*)(s);
  const float4 v1 = *(const float4*)(s + 4);
  const float vs[8] = {v0.x, v0.y, v0.z, v0.w, v1.x, v1.y, v1.z, v1.w};
  u32 hw[4], lw[4];
#pragma unroll
  for (int p = 0; p < 4; ++p) {
    float r0, r1;
    const u16 h0 = bf16_hi_rem(vs[2 * p], r0);
    const u16 h1 = bf16_hi_rem(vs[2 * p + 1], r1);
    hw[p] = (u32)h0 | ((u32)h1 << 16);
    lw[p] = (u32)bf16_rn(r0) | ((u32)bf16_rn(r1) << 16);
  }
  const size_t o = ((size_t)tl * 128 + b) * 1024 + k8;
  *(uint4*)(xh + o) = make_uint4(hw[0], hw[1], hw[2], hw[3]);
  *(uint4*)(xl + o) = make_uint4(lw[0], lw[1], lw[2], lw[3]);
}

// ---------------------------------------------------------------- MFMA GEMM
// C[M=T*128][N] = A[M][1024] @ B[N][1024]^T + bias, A/B pre-split bf16 (n-major, k-contig).
// MODE 0 (pre-gates): N=4096 (n'-order), bf16x3; C=preC[(tl*128+b)][4096].
// MODE 1 (out-proj):  N=1024, single product, C=out[b][t0+tl][1024].
// 128x128 tile, BK=32, 256 thr = 4 waves (2x2), per wave 4x4 frags of 16x16x32.
template<int MODE>
__global__ __launch_bounds__(256) void k_gemm_mfma(
    const u16* __restrict__ Ahg, const u16* __restrict__ Alg,
    const u16* __restrict__ Bhg, const u16* __restrict__ Blg,
    const float* __restrict__ bias,
    float* __restrict__ C, int t0)
{
  __shared__ u16 Ah[4096], Al[4096], Bh[4096], Bl[4096];
  const int tid = threadIdx.x;
  const int n0  = blockIdx.x * 128;
  const int by  = blockIdx.y;                 // = tl (one timestep per M-tile)

  const int w = tid >> 6, lane = tid & 63;
  const int wm = w >> 1, wn = w & 1;
  const int lr = lane & 15, lh = lane >> 4;   // frag row/col, k-half

  f32x4 acc[4][4];
#pragma unroll
  for (int mi = 0; mi < 4; ++mi)
#pragma unroll
    for (int ni = 0; ni < 4; ++ni) acc[mi][ni] = (f32x4){0.f, 0.f, 0.f, 0.f};

  const int srow  = tid >> 1;
  const int sb    = (tid & 1) * 2;
  const int swz   = (srow >> 1) & 3;
  const int l0 = srow * 32 + ((sb ^ swz) << 3);
  const int l1 = srow * 32 + (((sb + 1) ^ swz) << 3);
  const size_t ga = (size_t)(by * 128 + srow) * 1024 + (sb << 3);
  const size_t gb = (size_t)(n0 + srow) * 1024 + (sb << 3);

  int aoff[4], boff[4];
#pragma unroll
  for (int mi = 0; mi < 4; ++mi) {
    const int R = wm * 64 + mi * 16 + lr;
    aoff[mi] = R * 32 + ((lh ^ ((R >> 1) & 3)) << 3);
  }
#pragma unroll
  for (int ni = 0; ni < 4; ++ni) {
    const int Rn = wn * 64 + ni * 16 + lr;
    boff[ni] = Rn * 32 + ((lh ^ ((Rn >> 1) & 3)) << 3);
  }

  for (int k0 = 0; k0 < 1024; k0 += 32) {
    const uint4 vah0 = *(const uint4*)(Ahg + ga + k0);
    const uint4 vah1 = *(const uint4*)(Ahg + ga + k0 + 8);
    const uint4 vbh0 = *(const uint4*)(Bhg + gb + k0);
    const uint4 vbh1 = *(const uint4*)(Bhg + gb + k0 + 8);
    uint4 val0, val1, vbl0, vbl1;
    if (MODE == 0) {
      val0 = *(const uint4*)(Alg + ga + k0);
      val1 = *(const uint4*)(Alg + ga + k0 + 8);
      vbl0 = *(const uint4*)(Blg + gb + k0);
      vbl1 = *(const uint4*)(Blg + gb + k0 + 8);
    }
    __syncthreads();
    *(uint4*)(Ah + l0) = vah0; *(uint4*)(Ah + l1) = vah1;
    *(uint4*)(Bh + l0) = vbh0; *(uint4*)(Bh + l1) = vbh1;
    if (MODE == 0) {
      *(uint4*)(Al + l0) = val0; *(uint4*)(Al + l1) = val1;
      *(uint4*)(Bl + l0) = vbl0; *(uint4*)(Bl + l1) = vbl1;
    }
    __syncthreads();

    bf16x8 ahf[4], alf[4];
#pragma unroll
    for (int mi = 0; mi < 4; ++mi) {
      ahf[mi] = *(const bf16x8*)(&Ah[aoff[mi]]);
      if (MODE == 0) alf[mi] = *(const bf16x8*)(&Al[aoff[mi]]);
    }
#pragma unroll
    for (int ni = 0; ni < 4; ++ni) {
      const bf16x8 bhf = *(const bf16x8*)(&Bh[boff[ni]]);
      bf16x8 blf;
      if (MODE == 0) blf = *(const bf16x8*)(&Bl[boff[ni]]);
#pragma unroll
      for (int mi = 0; mi < 4; ++mi) {
        acc[mi][ni] = __builtin_amdgcn_mfma_f32_16x16x32_bf16(ahf[mi], bhf, acc[mi][ni], 0, 0, 0);
        if (MODE == 0) {
          acc[mi][ni] = __builtin_amdgcn_mfma_f32_16x16x32_bf16(ahf[mi], blf, acc[mi][ni], 0, 0, 0);
          acc[mi][ni] = __builtin_amdgcn_mfma_f32_16x16x32_bf16(alf[mi], bhf, acc[mi][ni], 0, 0, 0);
        }
      }
    }
  }

#pragma unroll
  for (int ni = 0; ni < 4; ++ni) {
    const int n = n0 + wn * 64 + ni * 16 + lr;
    const float bv = bias[n];
#pragma unroll
    for (int mi = 0; mi < 4; ++mi) {
      const int rb = wm * 64 + mi * 16 + lh * 4;
#pragma unroll
      for (int q = 0; q < 4; ++q) {
        const int r = rb + q;
        const float v = acc[mi][ni][q] + bv;
        if (MODE == 0) C[((size_t)by * 128 + r) * 4096 + n] = v;
        else           C[((size_t)r * 512 + (size_t)(t0 + by)) * 1024 + n] = v;
      }
    }
  }
}

// ---------------------------------------------------------------- MFMA scan step
// 256 blocks x 512 thr (8 waves). No LDS, no barriers.
// XCD-AWARE REMAP (the round-6 change): dispatch is round-robin over 8 XCDs,
// so bid&7 = XCD. Assign jt = (bid&7)*8 + ((bid>>3)&7), mq = bid>>6. All 4
// mq-sharers of a jt W-slice land on ONE XCD; per-XCD W working set =
// 8 slices x 256 KB = 2 MB -> Wht stays L2-resident instead of thrashing.
// Wave w: m-frag mi=w&1 (rows mq*32+mi*16..+15), n-frag nf=w>>1 (cols
// jt*64+nf*16..+15 of Wht n'-order). bf16x3: AhBh + AhBl + AlBh, fp32 acc.
// Epilogue: 12 shfl_xor gather the 4 gates per (b,j) cell; lane owns 1 cell.
__global__ __launch_bounds__(512) void k_step3(
    const u16* __restrict__ Whh, const u16* __restrict__ Whl,   // Wht hi/lo [4096][1024]
    const float* __restrict__ preC,       // [Tc][128][4096] n'-order
    const u16* __restrict__ hIh, const u16* __restrict__ hIl,   // h in, [128][1024]
    u16* __restrict__ hOh, u16* __restrict__ hOl,               // h out
    float* __restrict__ hT,               // fp32 h [j*128+b] (final output)
    float* __restrict__ cb, float* __restrict__ nb, float* __restrict__ mb,
    u16* __restrict__ hAllH,              // [Tc*128][1024] bf16 (out-GEMM A)
    int t_local)
{
  const int tid = threadIdx.x;
  const int bid = blockIdx.x;
  const int jt = (bid & 7) * 8 + ((bid >> 3) & 7);   // XCD-local jt grouping
  const int mq = bid >> 6;                           // 0..3
  const int w = tid >> 6, lane = tid & 63;
  const int mi = w & 1, nf = w >> 1;
  const int lr = lane & 15, lh = lane >> 4;
  const int rowb = mq * 32 + mi * 16;

  // this lane's epilogue cell
  const int G = lr & 3;                       // gate role / q-partition
  const int j = jt * 16 + nf * 4 + (lr >> 2);
  const int b = rowb + lh * 4 + G;
  const int sIdx = j * 128 + b;

  // prefetch pre-gates (one float4: n' = j*4 + g) and state
  const float4 pre4 = *(const float4*)(preC + (size_t)t_local * (128 * 4096)
                                       + (size_t)b * 4096 + j * 4);
  const float m_old = mb[sIdx];
  const float c_old = cb[sIdx];
  const float n_old = nb[sIdx];

  // fragment base pointers (16B-aligned; W slices L2-resident after remap)
  const u16* aH = hIh + (size_t)(rowb + lr) * 1024 + lh * 8;
  const u16* aL = hIl + (size_t)(rowb + lr) * 1024 + lh * 8;
  const u16* bH = Whh + (size_t)(jt * 64 + nf * 16 + lr) * 1024 + lh * 8;
  const u16* bL = Whl + (size_t)(jt * 64 + nf * 16 + lr) * 1024 + lh * 8;

  f32x4 acc = {0.f, 0.f, 0.f, 0.f};
#pragma unroll 4
  for (int k0 = 0; k0 < 1024; k0 += 32) {
    const bf16x8 ah = *(const bf16x8*)(aH + k0);
    const bf16x8 al = *(const bf16x8*)(aL + k0);
    const bf16x8 bh = *(const bf16x8*)(bH + k0);
    const bf16x8 bl = *(const bf16x8*)(bL + k0);
    acc = __builtin_amdgcn_mfma_f32_16x16x32_bf16(ah, bh, acc, 0, 0, 0);
    acc = __builtin_amdgcn_mfma_f32_16x16x32_bf16(ah, bl, acc, 0, 0, 0);
    acc = __builtin_amdgcn_mfma_f32_16x16x32_bf16(al, bh, acc, 0, 0, 0);
  }

  // gather 4 gates per cell: gate t value = s_{G^t}[G] (all compile-time per case)
  const float a0 = acc[0], a1 = acc[1], a2 = acc[2], a3 = acc[3];
  const float s10 = __shfl_xor(a0, 1), s11 = __shfl_xor(a1, 1),
              s12 = __shfl_xor(a2, 1), s13 = __shfl_xor(a3, 1);
  const float s20 = __shfl_xor(a0, 2), s21 = __shfl_xor(a1, 2),
              s22 = __shfl_xor(a2, 2), s23 = __shfl_xor(a3, 2);
  const float s30 = __shfl_xor(a0, 3), s31 = __shfl_xor(a1, 3),
              s32 = __shfl_xor(a2, 3), s33 = __shfl_xor(a3, 3);
  float fv, iv, cv, ov;
  if      (G == 0) { fv = a0;  iv = s10; cv = s20; ov = s30; }
  else if (G == 1) { fv = s11; iv = a1;  cv = s31; ov = s21; }
  else if (G == 2) { fv = s22; iv = s32; cv = a2;  ov = s12; }
  else             { fv = s33; iv = s23; cv = s13; ov = a3;  }

  // fused elementwise state update
  const float f_log = fv + pre4.x;
  const float i_log = iv + pre4.y;
  const float c_log = cv + pre4.z;
  const float o_log = ov + pre4.w;

  const float m_new = fmaxf(f_log + m_old, i_log);
  const float i_t   = expf(i_log - m_new);
  const float f_t   = expf(f_log + m_old - m_new);
  const float c_hat = tanhf(c_log);
  const float o_t   = 1.0f / (1.0f + expf(-o_log));
  const float c_new = f_t * c_old + i_t * c_hat;
  const float n_new = f_t * n_old + i_t;
  const float h_new = o_t * (c_new / (n_new + 1e-8f));

  cb[sIdx] = c_new;
  nb[sIdx] = n_new;
  mb[sIdx] = m_new;
  hT[sIdx] = h_new;                               // fp32 (final-state output)

  float rem;
  const u16 hh = bf16_hi_rem(h_new, rem);
  const u16 hl = bf16_rn(rem);
  hOh[(size_t)b * 1024 + j] = hh;                 // recurrence h hi/lo
  hOl[(size_t)b * 1024 + j] = hl;
  hAllH[((size_t)t_local * 128 + b) * 1024 + j] = hh;
}

// ---------------------------------------------------------------- final state tail
__global__ __launch_bounds__(256) void k_tail(
    const float* __restrict__ hT, const float* __restrict__ cbp,
    const float* __restrict__ nbp, const float* __restrict__ mbp,
    float* __restrict__ dst)
{
  const int gid = blockIdx.x * 256 + threadIdx.x;   // [0, 4*131072)
  const int q = gid >> 17, rem = gid & 131071;
  const int b = rem >> 10, j = rem & 1023;
  const float* src = (q == 0) ? hT : (q == 1) ? cbp : (q == 2) ? nbp : mbp;
  dst[gid] = src[j * B_ + b];
}

// ---------------------------------------------------------------- launch
extern "C" void kernel_launch(void* const* d_in, const int* in_sizes, int n_in,
                              void* d_out, int out_size, void* d_ws, size_t ws_size,
                              hipStream_t stream) {
  const float* x    = (const float*)d_in[0];
  const float* Wf   = (const float*)d_in[1];
  const float* bfv  = (const float*)d_in[2];
  const float* Wi   = (const float*)d_in[3];
  const float* biv  = (const float*)d_in[4];
  const float* Wc   = (const float*)d_in[5];
  const float* bcv  = (const float*)d_in[6];
  const float* Wo   = (const float*)d_in[7];
  const float* bov  = (const float*)d_in[8];
  const float* Wout = (const float*)d_in[9];
  const float* bout = (const float*)d_in[10];
  float* out = (float*)d_out;

  float* base = (float*)d_ws;
  float* hT = base;                       // 131072 f
  float* cb = base + 131072;
  float* nb = base + 2 * 131072;
  float* mb = base + 3 * 131072;
  u16* hH0h = (u16*)(base + 4 * 131072);  // 4 x 131072 u16 = 2*131072 f
  u16* hH0l = hH0h + 131072;
  u16* hH1h = hH0l + 131072;
  u16* hH1l = hH1h + 131072;
  u16* Wxt_hi = (u16*)(base + 6 * 131072);
  u16* Wxt_lo = Wxt_hi + 4194304;
  u16* Wht_hi = Wxt_lo + 4194304;
  u16* Wht_lo = Wht_hi + 4194304;
  u16* Wot_hi = Wht_lo + 4194304;
  u16* Wot_lo = Wot_hi + 1048576;
  float* bias4  = (float*)(Wot_lo + 1048576);
  float* chunk0 = bias4 + 4096;

  // fixed floats: 6*131072 + (4*4194304 + 2*1048576) u16 /2 + 4096
  const size_t fixedF2 = (size_t)6 * 131072
                       + ((size_t)4 * 4194304 + 2 * 1048576) / 2
                       + 4096;
  // per timestep: preC 2MB + xs hi/lo 0.5MB + hAllH 0.25MB = 720896 floats
  const size_t perTF = (size_t)128 * 4096 + 3 * 65536;
  const size_t availF = (ws_size / 4 > fixedF2) ? (ws_size / 4 - fixedF2) : 0;
  int Tc = (int)(availF / perTF);
  if (Tc > S_) Tc = S_;
  if (Tc < 1)  Tc = 1;

  float* preC   = chunk0;                               // [Tc][128][4096] n'-order
  u16*   xs_hi  = (u16*)(preC + (size_t)Tc * 524288);   // [Tc*128][1024]
  u16*   xs_lo  = xs_hi + (size_t)Tc * 131072;
  u16*   hAll_h = xs_lo + (size_t)Tc * 131072;          // [Tc*128][1024]

  u16* hHi[2] = {hH0h, hH1h};
  u16* hLo[2] = {hH0l, hH1l};

  // one-time prep: zero c/n/m + h(0) hi/lo; build W operand images + bias
  k_zero<<<2048, 256, 0, stream>>>(cb, 4 * 131072);     // cb,nb,mb + hH0h,hH0l
  k_tr<<<dim3(16, 16, 9), 256, 0, stream>>>(Wf, Wi, Wc, Wo, Wout,
                                            Wxt_hi, Wxt_lo, Wot_hi, Wot_lo,
                                            Wht_hi, Wht_lo);
  k_bias<<<16, 256, 0, stream>>>(bfv, biv, bcv, bov, bias4);

  for (int t0 = 0; t0 < S_; t0 += Tc) {
    const int T = (S_ - t0 < Tc) ? (S_ - t0) : Tc;

    k_xsplit<<<dim3(64, T), 256, 0, stream>>>(x, xs_hi, xs_lo, t0);
    k_gemm_mfma<0><<<dim3(32, T), 256, 0, stream>>>(xs_hi, xs_lo, Wxt_hi, Wxt_lo,
                                                    bias4, preC, t0);
    for (int tl = 0; tl < T; ++tl) {
      const int tg = t0 + tl;
      const int ri = tg & 1, wi = ri ^ 1;
      k_step3<<<256, 512, 0, stream>>>(Wht_hi, Wht_lo, preC,
                                       hHi[ri], hLo[ri], hHi[wi], hLo[wi],
                                       hT, cb, nb, mb, hAll_h, tl);
    }
    k_gemm_mfma<1><<<dim3(8, T), 256, 0, stream>>>(hAll_h, hAll_h, Wot_hi, Wot_hi,
                                                   bout, out, t0);
  }

  k_tail<<<2048, 256, 0, stream>>>(hT, cb, nb, mb, out + (size_t)B_ * S_ * H_);
}